// Round 5
// baseline (86.217 us; speedup 1.0000x reference)
//
#include <hip/hip_runtime.h>
#include <math.h>

#define N_IMG 512
#define N_ANGLES 25
#define N_DET 512
#define DET_SPACING 3.0f
#define SRC_DIST 512.0f
#define DET_DIST 512.0f
#define N_SAMPLES 1024

#define TILE 64
#define TPB 8            // tiles per side (512/64)
#define HALO_W 66        // TILE + 2 (1-px halo each side)
#define LDS_STRIDE 67    // odd stride -> bank-conflict friendly

// Clip [tlo,thi] to { t : lo <= v0 + t*dv <= hi }.
__device__ __forceinline__ void slab(float v0, float dv, float lo, float hi,
                                     float& tlo, float& thi) {
    if (fabsf(dv) < 1e-8f) {
        if (v0 < lo || v0 > hi) { tlo = 1.0f; thi = 0.0f; }   // empty
    } else {
        float inv = 1.0f / dv;
        float ta = (lo - v0) * inv;
        float tb = (hi - v0) * inv;
        tlo = fmaxf(tlo, fminf(ta, tb));
        thi = fminf(thi, fmaxf(ta, tb));
    }
}

__global__ __launch_bounds__(256) void zero_out(float* __restrict__ out) {
    int i = blockIdx.x * blockDim.x + threadIdx.x;
    if (i < N_ANGLES * N_DET) out[i] = 0.0f;
}

// One block = (angle, 64x64 image tile).  Tile+halo staged in LDS with zeros
// outside the image (== reference's per-corner masking).  Ownership boxes are
// half-open and computed with identical float arithmetic in every block, so
// each sample index i of each ray is claimed by exactly one tile.
__global__ __launch_bounds__(256) void fanbeam_tiles(const float* __restrict__ img,
                                                     float* __restrict__ out) {
    __shared__ float tile[HALO_W * LDS_STRIDE];
    __shared__ unsigned int entries[N_DET];
    __shared__ int n_entries;

    const int a  = blockIdx.x / (TPB * TPB);
    const int tl = blockIdx.x % (TPB * TPB);
    const int tr = tl / TPB, tc = tl % TPB;
    const int x0 = tc * TILE, y0 = tr * TILE;   // tile origin in pixel coords
    const int tid = threadIdx.x;

    // --- stage tile + halo (zero outside image) ---
    for (int idx = tid; idx < HALO_W * HALO_W; idx += 256) {
        int lr = idx / HALO_W, lc = idx - lr * HALO_W;
        int gy = y0 - 1 + lr, gx = x0 - 1 + lc;
        float v = 0.0f;
        if ((unsigned)gy < N_IMG && (unsigned)gx < N_IMG) v = img[(gy << 9) + gx];
        tile[lr * LDS_STRIDE + lc] = v;
    }
    if (tid == 0) n_entries = 0;

    // --- block-uniform geometry (double trig once per block for accuracy) ---
    double beta = (2.0 * M_PI) * (double)a / (double)N_ANGLES;
    float cb = (float)cos(beta), sb = (float)sin(beta);
    float srcx = -SRC_DIST * sb, srcy = SRC_DIST * cb;
    const float half = (N_IMG - 1) * 0.5f;      // 255.5
    const float col0 = srcx + half;
    const float row0 = half - srcy;
    const float inv_n = 1.0f / N_SAMPLES;

    // Ownership box (half-open [lo, hi)).  Edge tiles absorb the out-of-image
    // band where partial bilinear footprints still touch the image; beyond
    // (-1, 512) every contribution is exactly zero.
    const float xlo = (tc == 0)       ? -1.0f  : (float)x0;
    const float xhi = (tc == TPB - 1) ? 512.0f : (float)(x0 + TILE);
    const float ylo = (tr == 0)       ? -1.0f  : (float)y0;
    const float yhi = (tr == TPB - 1) ? 512.0f : (float)(y0 + TILE);

    __syncthreads();

    // --- clip every ray against the ownership box, build compact work list ---
    for (int det = tid; det < N_DET; det += 256) {
        float t  = ((float)det - (N_DET - 1) * 0.5f) * DET_SPACING;
        float dx = (t * cb + DET_DIST * sb) - srcx;
        float dy = (t * sb - DET_DIST * cb) - srcy;
        float drow = -dy;
        float tA = 0.0f, tB = 1.0f;
        slab(col0, dx,   xlo - 0.01f, xhi + 0.01f, tA, tB);
        slab(row0, drow, ylo - 0.01f, yhi + 0.01f, tA, tB);
        if (tA <= tB) {
            int i_lo = max(0,             (int)floorf(tA * N_SAMPLES - 0.5f) - 1);
            int i_hi = min(N_SAMPLES - 1, (int)ceilf (tB * N_SAMPLES - 0.5f) + 1);
            int cnt = i_hi - i_lo + 1;   // <= ~95 (box diag 90.5 / step >= 1.0)
            if (cnt > 0) {
                int slot = atomicAdd(&n_entries, 1);
                // det:9 bits | i_lo:10 bits | cnt:13 bits
                entries[slot] = (unsigned)det | ((unsigned)i_lo << 9)
                              | ((unsigned)cnt << 19);
            }
        }
    }
    __syncthreads();

    // --- one wave per work-list entry; bilinear from LDS ---
    const int wave = tid >> 6, lane = tid & 63;
    const int n = n_entries;
    for (int e = wave; e < n; e += 4) {
        unsigned ent = entries[e];
        int det  = ent & 511;
        int i_lo = (ent >> 9) & 1023;
        int cnt  = (int)(ent >> 19);
        float t  = ((float)det - (N_DET - 1) * 0.5f) * DET_SPACING;
        float dx = (t * cb + DET_DIST * sb) - srcx;
        float dy = (t * sb - DET_DIST * cb) - srcy;
        float drow = -dy;
        float seg = sqrtf(dx * dx + dy * dy);
        float acc = 0.0f;
        for (int k = lane; k < cnt; k += 64) {
            float ts  = ((float)(i_lo + k) + 0.5f) * inv_n;
            float col = fmaf(ts, dx,   col0);
            float row = fmaf(ts, drow, row0);
            // exact ownership predicate (the clip range above is conservative)
            if (col >= xlo && col < xhi && row >= ylo && row < yhi) {
                float cf = floorf(col), rf = floorf(row);
                float fc = col - cf,    fr = row - rf;
                int lc = (int)cf - x0 + 1;   // in [0,65]
                int lr = (int)rf - y0 + 1;   // in [0,65]
                const float* p = &tile[lr * LDS_STRIDE + lc];
                float v00 = p[0],          v01 = p[1];
                float v10 = p[LDS_STRIDE], v11 = p[LDS_STRIDE + 1];
                float top = fmaf(fc, v01 - v00, v00);
                float bot = fmaf(fc, v11 - v10, v10);
                acc += fmaf(fr, bot - top, top);
            }
        }
        #pragma unroll
        for (int off = 32; off > 0; off >>= 1)
            acc += __shfl_down(acc, off, 64);
        if (lane == 0)
            atomicAdd(&out[(a << 9) + det], acc * (seg * inv_n));
    }
}

extern "C" void kernel_launch(void* const* d_in, const int* in_sizes, int n_in,
                              void* d_out, int out_size, void* d_ws, size_t ws_size,
                              hipStream_t stream) {
    const float* img = (const float*)d_in[0];
    float* out = (float*)d_out;

    zero_out<<<(N_ANGLES * N_DET + 255) / 256, 256, 0, stream>>>(out);
    fanbeam_tiles<<<N_ANGLES * TPB * TPB, 256, 0, stream>>>(img, out);
}

// Round 6
// 74.133 us; speedup vs baseline: 1.1630x; 1.1630x over previous
//
#include <hip/hip_runtime.h>
#include <math.h>

#define N_IMG 512
#define N_ANGLES 25
#define N_DET 512
#define DET_SPACING 3.0f
#define SRC_DIST 512.0f
#define DET_DIST 512.0f
#define N_SAMPLES 1024

// ---------------------------------------------------------------------------
// Pair-packed copies of the image in workspace (ws re-poison is a fixed cost
// the harness pays whether or not we use ws — measured R3 vs R2).
//   H[r*512+c] = { img[r][c], img[r+1][c] }   (contiguous in c; r+1 clamped)
//   V[c*512+r] = { img[r][c], img[r][c+1] }   (contiguous in r; c+1 clamped)
// A ray samples H if it advances columns fastest, else V: the two 8-byte
// gathers per sample then land on line-shared addresses across lanes,
// cutting L2 line traffic ~4x (the measured bottleneck of the flat kernel).
// ---------------------------------------------------------------------------
__global__ __launch_bounds__(256) void build_pairs(const float* __restrict__ img,
                                                   float2* __restrict__ H,
                                                   float2* __restrict__ V) {
    int idx = blockIdx.x * blockDim.x + threadIdx.x;   // 0 .. 512*512-1
    int r = idx >> 9, c = idx & 511;
    float a  = img[idx];
    float dn = img[(min(r + 1, N_IMG - 1) << 9) + c];
    float rt = img[(r << 9) + min(c + 1, N_IMG - 1)];
    H[idx] = make_float2(a, dn);
    V[(c << 9) + r] = make_float2(a, rt);
}

// Reference-exact masked bilinear sample (boundary bands only).
__device__ __forceinline__ float masked_sample(const float* __restrict__ img,
                                               float col, float row) {
    float rf = floorf(row), cf = floorf(col);
    float fr = row - rf,    fc = col - cf;
    int r0 = (int)rf, c0 = (int)cf;
    float wr0 = (r0 >=  0 && r0 < N_IMG)     ? (1.0f - fr) : 0.0f;
    float wr1 = (r0 >= -1 && r0 < N_IMG - 1) ? fr          : 0.0f;
    float wc0 = (c0 >=  0 && c0 < N_IMG)     ? (1.0f - fc) : 0.0f;
    float wc1 = (c0 >= -1 && c0 < N_IMG - 1) ? fc          : 0.0f;
    int rc0 = min(max(r0,     0), N_IMG - 1);
    int rc1 = min(max(r0 + 1, 0), N_IMG - 1);
    int cc0 = min(max(c0,     0), N_IMG - 1);
    int cc1 = min(max(c0 + 1, 0), N_IMG - 1);
    float v00 = img[(rc0 << 9) + cc0];
    float v01 = img[(rc0 << 9) + cc1];
    float v10 = img[(rc1 << 9) + cc0];
    float v11 = img[(rc1 << 9) + cc1];
    return wr0 * (wc0 * v00 + wc1 * v01) + wr1 * (wc0 * v10 + wc1 * v11);
}

// Clip [tlo,thi] to { t : lo <= v0 + t*dv <= hi }.
__device__ __forceinline__ void slab(float v0, float dv, float lo, float hi,
                                     float& tlo, float& thi) {
    if (fabsf(dv) < 1e-8f) {
        if (v0 < lo || v0 > hi) { tlo = 1.0f; thi = 0.0f; }   // empty
    } else {
        float inv = 1.0f / dv;
        float ta = (lo - v0) * inv;
        float tb = (hi - v0) * inv;
        tlo = fmaxf(tlo, fminf(ta, tb));
        thi = fminf(thi, fmaxf(ta, tb));
    }
}

__global__ __launch_bounds__(256) void fanbeam_kernel(const float* __restrict__ img,
                                                      const float2* __restrict__ H,
                                                      const float2* __restrict__ V,
                                                      float* __restrict__ out) {
    const int gid  = blockIdx.x * blockDim.x + threadIdx.x;
    const int ray  = gid >> 6;          // one wave64 per ray
    const int lane = threadIdx.x & 63;
    if (ray >= N_ANGLES * N_DET) return;

    const int a = ray / N_DET;
    const int d = ray - a * N_DET;

    double beta = (2.0 * M_PI) * (double)a / (double)N_ANGLES;
    float c = (float)cos(beta);
    float s = (float)sin(beta);
    float t = ((float)d - (N_DET - 1) * 0.5f) * DET_SPACING;
    float srcx = -SRC_DIST * s;
    float srcy =  SRC_DIST * c;
    float dx = (t * c + DET_DIST * s) - srcx;
    float dy = (t * s - DET_DIST * c) - srcy;
    float seg = sqrtf(dx * dx + dy * dy);

    const float half = (N_IMG - 1) * 0.5f;   // 255.5
    const float col0 = srcx + half;
    const float row0 = half - srcy;
    const float drow = -dy;
    const float inv_n = 1.0f / N_SAMPLES;

    // Outer window: outside col/row in (-1, 512) every corner weight is 0.
    float tA = 0.0f, tB = 1.0f;
    slab(col0, dx,   -1.01f, 512.01f, tA, tB);
    slab(row0, drow, -1.01f, 512.01f, tA, tB);
    int i_lo, i_hi;
    if (tB < tA) { i_lo = 1; i_hi = 0; }
    else {
        i_lo = max(0,             (int)floorf(tA * N_SAMPLES - 0.5f) - 1);
        i_hi = min(N_SAMPLES - 1, (int)ceilf (tB * N_SAMPLES - 0.5f) + 1);
    }

    // Interior window: col,row in [0.01, 510.99] -> r0,c0 in [0,510], all
    // four corners valid; pair arrays cover r0+1/c0+1 up to index 511.
    float tC = 0.0f, tD = 1.0f;
    slab(col0, dx,   0.01f, 510.99f, tC, tD);
    slab(row0, drow, 0.01f, 510.99f, tC, tD);
    int j_lo, j_hi;
    if (tD < tC) { j_lo = 1; j_hi = 0; }
    else {
        j_lo = (int)ceilf (tC * N_SAMPLES - 0.5f) + 1;
        j_hi = (int)floorf(tD * N_SAMPLES - 0.5f) - 1;
    }
    j_lo = max(j_lo, i_lo);
    j_hi = min(j_hi, i_hi);

    float acc = 0.0f;

    if (j_lo > j_hi) {
        for (int i = i_lo + lane; i <= i_hi; i += 64) {
            float ts  = ((float)i + 0.5f) * inv_n;
            acc += masked_sample(img, fmaf(ts, dx, col0), fmaf(ts, drow, row0));
        }
    } else {
        // Leading boundary band (reference-exact masked path).
        for (int i = i_lo + lane; i < j_lo; i += 64) {
            float ts  = ((float)i + 0.5f) * inv_n;
            acc += masked_sample(img, fmaf(ts, dx, col0), fmaf(ts, drow, row0));
        }
        // Interior fast path: 2 gathers of adjacent float2 along the fast axis.
        if (fabsf(dx) >= fabsf(drow)) {
            #pragma unroll 2
            for (int i = j_lo + lane; i <= j_hi; i += 64) {
                float ts  = ((float)i + 0.5f) * inv_n;
                float col = fmaf(ts, dx,   col0);
                float row = fmaf(ts, drow, row0);
                float cf = floorf(col), rf = floorf(row);
                float fc = col - cf,    fr = row - rf;
                int ci = min(max((int)cf, 0), N_IMG - 2);
                int ri = min(max((int)rf, 0), N_IMG - 2);
                float2 g1 = H[(ri << 9) + ci];       // (v00, v10)
                float2 g2 = H[(ri << 9) + ci + 1];   // (v01, v11)
                float A = fmaf(fr, g1.y - g1.x, g1.x);
                float B = fmaf(fr, g2.y - g2.x, g2.x);
                acc += fmaf(fc, B - A, A);
            }
        } else {
            #pragma unroll 2
            for (int i = j_lo + lane; i <= j_hi; i += 64) {
                float ts  = ((float)i + 0.5f) * inv_n;
                float col = fmaf(ts, dx,   col0);
                float row = fmaf(ts, drow, row0);
                float cf = floorf(col), rf = floorf(row);
                float fc = col - cf,    fr = row - rf;
                int ci = min(max((int)cf, 0), N_IMG - 2);
                int ri = min(max((int)rf, 0), N_IMG - 2);
                float2 g1 = V[(ci << 9) + ri];       // (v00, v01)
                float2 g2 = V[(ci << 9) + ri + 1];   // (v10, v11)
                float A = fmaf(fc, g1.y - g1.x, g1.x);
                float B = fmaf(fc, g2.y - g2.x, g2.x);
                acc += fmaf(fr, B - A, A);
            }
        }
        // Trailing boundary band.
        for (int i = max(j_hi + 1, i_lo) + lane; i <= i_hi; i += 64) {
            float ts  = ((float)i + 0.5f) * inv_n;
            acc += masked_sample(img, fmaf(ts, dx, col0), fmaf(ts, drow, row0));
        }
    }

    #pragma unroll
    for (int off = 32; off > 0; off >>= 1)
        acc += __shfl_down(acc, off, 64);

    if (lane == 0) out[ray] = acc * (seg * inv_n);
}

extern "C" void kernel_launch(void* const* d_in, const int* in_sizes, int n_in,
                              void* d_out, int out_size, void* d_ws, size_t ws_size,
                              hipStream_t stream) {
    const float* img = (const float*)d_in[0];
    float* out = (float*)d_out;
    float2* H = (float2*)d_ws;                          // 2 MB
    float2* V = (float2*)((char*)d_ws + (size_t)N_IMG * N_IMG * sizeof(float2));

    build_pairs<<<(N_IMG * N_IMG) / 256, 256, 0, stream>>>(img, H, V);

    const int n_rays = N_ANGLES * N_DET;                // 12800
    const int threads = 256;                            // 4 waves = 4 rays/block
    const int blocks = (n_rays * 64 + threads - 1) / threads;   // 3200
    fanbeam_kernel<<<blocks, threads, 0, stream>>>(img, H, V, out);
}

// Round 8
// 73.381 us; speedup vs baseline: 1.1749x; 1.0103x over previous
//
#include <hip/hip_runtime.h>
#include <math.h>

#define N_IMG 512
#define N_ANGLES 25
#define N_DET 512
#define DET_SPACING 3.0f
#define SRC_DIST 512.0f
#define DET_DIST 512.0f
#define N_SAMPLES 1024

// ws layout (exactly 4 MB used):  H (2 MB) | V (2 MB)
// H[r*512+c] = { img[r][c], img[r+1][c] }   (contiguous in c; r+1 clamped)
// V[c*512+r] = { img[r][c], img[r][c+1] }   (contiguous in r; c+1 clamped)
__global__ __launch_bounds__(256) void build_pairs(const float* __restrict__ img,
                                                   float2* __restrict__ H,
                                                   float2* __restrict__ V) {
    int idx = blockIdx.x * blockDim.x + threadIdx.x;   // 0 .. 512*512-1
    int r = idx >> 9, c = idx & 511;
    float a  = img[idx];
    float dn = img[(min(r + 1, N_IMG - 1) << 9) + c];
    float rt = img[(r << 9) + min(c + 1, N_IMG - 1)];
    H[idx] = make_float2(a, dn);
    V[(c << 9) + r] = make_float2(a, rt);
}

// Reference-exact masked bilinear sample (boundary bands only).
__device__ __forceinline__ float masked_sample(const float* __restrict__ img,
                                               float col, float row) {
    float rf = floorf(row), cf = floorf(col);
    float fr = row - rf,    fc = col - cf;
    int r0 = (int)rf, c0 = (int)cf;
    float wr0 = (r0 >=  0 && r0 < N_IMG)     ? (1.0f - fr) : 0.0f;
    float wr1 = (r0 >= -1 && r0 < N_IMG - 1) ? fr          : 0.0f;
    float wc0 = (c0 >=  0 && c0 < N_IMG)     ? (1.0f - fc) : 0.0f;
    float wc1 = (c0 >= -1 && c0 < N_IMG - 1) ? fc          : 0.0f;
    int rc0 = min(max(r0,     0), N_IMG - 1);
    int rc1 = min(max(r0 + 1, 0), N_IMG - 1);
    int cc0 = min(max(c0,     0), N_IMG - 1);
    int cc1 = min(max(c0 + 1, 0), N_IMG - 1);
    float v00 = img[(rc0 << 9) + cc0];
    float v01 = img[(rc0 << 9) + cc1];
    float v10 = img[(rc1 << 9) + cc0];
    float v11 = img[(rc1 << 9) + cc1];
    return wr0 * (wc0 * v00 + wc1 * v01) + wr1 * (wc0 * v10 + wc1 * v11);
}

// Clip [tlo,thi] to { t : lo <= v0 + t*dv <= hi }.
__device__ __forceinline__ void slab(float v0, float dv, float lo, float hi,
                                     float& tlo, float& thi) {
    if (fabsf(dv) < 1e-8f) {
        if (v0 < lo || v0 > hi) { tlo = 1.0f; thi = 0.0f; }   // empty
    } else {
        float inv = 1.0f / dv;
        float ta = (lo - v0) * inv;
        float tb = (hi - v0) * inv;
        tlo = fmaxf(tlo, fminf(ta, tb));
        thi = fminf(thi, fmaxf(ta, tb));
    }
}

__global__ __launch_bounds__(256) void fanbeam_kernel(const float* __restrict__ img,
                                                      const float2* __restrict__ H,
                                                      const float2* __restrict__ V,
                                                      float* __restrict__ out) {
    const int gid  = blockIdx.x * blockDim.x + threadIdx.x;
    const int ray  = gid >> 6;          // one wave64 per ray
    const int lane = threadIdx.x & 63;
    if (ray >= N_ANGLES * N_DET) return;

    const int a = ray / N_DET;
    const int d = ray - a * N_DET;

    // f32 trig on an exactly-representable fraction of 2: beta/pi = 2a/25.
    // Error vs the reference's f64 path is ~1e-7 rad -> ~6e-5 px at the
    // source point — far inside the validation tolerance (and the f64 libm
    // sequence per wave was the R6 kernel's dominant cost).
    float frac = 2.0f * (float)a / 25.0f;          // beta / pi
    float beta = frac * 3.14159265358979323846f;
    float c, s;
    __sincosf(beta, &s, &c);
    float t = ((float)d - (N_DET - 1) * 0.5f) * DET_SPACING;
    float srcx = -SRC_DIST * s;
    float srcy =  SRC_DIST * c;
    float dx = (t * c + DET_DIST * s) - srcx;
    float dy = (t * s - DET_DIST * c) - srcy;
    float seg = sqrtf(dx * dx + dy * dy);

    const float half = (N_IMG - 1) * 0.5f;   // 255.5
    const float col0 = srcx + half;
    const float row0 = half - srcy;
    const float drow = -dy;
    const float inv_n = 1.0f / N_SAMPLES;

    // Outer window: outside col/row in (-1, 512) every corner weight is 0.
    float tA = 0.0f, tB = 1.0f;
    slab(col0, dx,   -1.01f, 512.01f, tA, tB);
    slab(row0, drow, -1.01f, 512.01f, tA, tB);
    int i_lo, i_hi;
    if (tB < tA) { i_lo = 1; i_hi = 0; }
    else {
        i_lo = max(0,             (int)floorf(tA * N_SAMPLES - 0.5f) - 1);
        i_hi = min(N_SAMPLES - 1, (int)ceilf (tB * N_SAMPLES - 0.5f) + 1);
    }

    // Interior window: col,row in [0.01, 510.99] -> r0,c0 in [0,510], all
    // four corners valid; pair arrays cover r0+1/c0+1 up to index 511.
    float tC = 0.0f, tD = 1.0f;
    slab(col0, dx,   0.01f, 510.99f, tC, tD);
    slab(row0, drow, 0.01f, 510.99f, tC, tD);
    int j_lo, j_hi;
    if (tD < tC) { j_lo = 1; j_hi = 0; }
    else {
        j_lo = (int)ceilf (tC * N_SAMPLES - 0.5f) + 1;
        j_hi = (int)floorf(tD * N_SAMPLES - 0.5f) - 1;
    }
    j_lo = max(j_lo, i_lo);
    j_hi = min(j_hi, i_hi);

    float acc = 0.0f;

    if (j_lo > j_hi) {
        for (int i = i_lo + lane; i <= i_hi; i += 64) {
            float ts  = ((float)i + 0.5f) * inv_n;
            acc += masked_sample(img, fmaf(ts, dx, col0), fmaf(ts, drow, row0));
        }
    } else {
        // Leading boundary band (reference-exact masked path).
        for (int i = i_lo + lane; i < j_lo; i += 64) {
            float ts  = ((float)i + 0.5f) * inv_n;
            acc += masked_sample(img, fmaf(ts, dx, col0), fmaf(ts, drow, row0));
        }
        // Interior fast path: 2 gathers of adjacent float2 along the fast axis.
        if (fabsf(dx) >= fabsf(drow)) {
            #pragma unroll 2
            for (int i = j_lo + lane; i <= j_hi; i += 64) {
                float ts  = ((float)i + 0.5f) * inv_n;
                float col = fmaf(ts, dx,   col0);
                float row = fmaf(ts, drow, row0);
                float cf = floorf(col), rf = floorf(row);
                float fc = col - cf,    fr = row - rf;
                int ci = min(max((int)cf, 0), N_IMG - 2);
                int ri = min(max((int)rf, 0), N_IMG - 2);
                float2 g1 = H[(ri << 9) + ci];       // (v00, v10)
                float2 g2 = H[(ri << 9) + ci + 1];   // (v01, v11)
                float A = fmaf(fr, g1.y - g1.x, g1.x);
                float B = fmaf(fr, g2.y - g2.x, g2.x);
                acc += fmaf(fc, B - A, A);
            }
        } else {
            #pragma unroll 2
            for (int i = j_lo + lane; i <= j_hi; i += 64) {
                float ts  = ((float)i + 0.5f) * inv_n;
                float col = fmaf(ts, dx,   col0);
                float row = fmaf(ts, drow, row0);
                float cf = floorf(col), rf = floorf(row);
                float fc = col - cf,    fr = row - rf;
                int ci = min(max((int)cf, 0), N_IMG - 2);
                int ri = min(max((int)rf, 0), N_IMG - 2);
                float2 g1 = V[(ci << 9) + ri];       // (v00, v01)
                float2 g2 = V[(ci << 9) + ri + 1];   // (v10, v11)
                float A = fmaf(fc, g1.y - g1.x, g1.x);
                float B = fmaf(fc, g2.y - g2.x, g2.x);
                acc += fmaf(fr, B - A, A);
            }
        }
        // Trailing boundary band.
        for (int i = max(j_hi + 1, i_lo) + lane; i <= i_hi; i += 64) {
            float ts  = ((float)i + 0.5f) * inv_n;
            acc += masked_sample(img, fmaf(ts, dx, col0), fmaf(ts, drow, row0));
        }
    }

    #pragma unroll
    for (int off = 32; off > 0; off >>= 1)
        acc += __shfl_down(acc, off, 64);

    if (lane == 0) out[ray] = acc * (seg * inv_n);
}

extern "C" void kernel_launch(void* const* d_in, const int* in_sizes, int n_in,
                              void* d_out, int out_size, void* d_ws, size_t ws_size,
                              hipStream_t stream) {
    const float* img = (const float*)d_in[0];
    float* out = (float*)d_out;
    const size_t pair_bytes = (size_t)N_IMG * N_IMG * sizeof(float2);
    float2* H  = (float2*)d_ws;                            // 2 MB
    float2* V  = (float2*)((char*)d_ws + pair_bytes);      // 2 MB

    build_pairs<<<(N_IMG * N_IMG) / 256, 256, 0, stream>>>(img, H, V);

    const int n_rays = N_ANGLES * N_DET;                   // 12800
    const int threads = 256;                               // 4 waves = 4 rays/block
    const int blocks = (n_rays * 64 + threads - 1) / threads;   // 3200
    fanbeam_kernel<<<blocks, threads, 0, stream>>>(img, H, V, out);
}

// Round 9
// 71.858 us; speedup vs baseline: 1.1998x; 1.0212x over previous
//
#include <hip/hip_runtime.h>
#include <math.h>

#define N_IMG 512
#define N_ANGLES 25
#define N_DET 512
#define DET_SPACING 3.0f
#define SRC_DIST 512.0f
#define DET_DIST 512.0f
#define N_SAMPLES 1024

// ---------------------------------------------------------------------------
// ws layout: 4 MB of 2x2-BLOCKED quads.
//   quad(r,c) = { img[r][c], img[r][c+1], img[r+1][c], img[r+1][c+1] }
//   stored at index ((r>>1)<<10) + ((c>>1)<<2) + ((r&1)<<1) + (c&1)
// One 64 B cache line = 4 quads = a 2x2-pixel patch, so a ray advancing
// ~1.4 px/sample reuses the same line ~2x in ANY direction (the R6 pair
// layout only had line locality for near-axis rays — measured line-traffic
// model fit; diagonal rays touched a fresh line every sample).
// Interior fast path only reads r,c <= 510, so the +1 clamps in the build
// never feed wrong data to it.
// ---------------------------------------------------------------------------
__device__ __forceinline__ int quad_index(int r, int c) {
    return ((r >> 1) << 10) + ((c >> 1) << 2) + ((r & 1) << 1) + (c & 1);
}

__global__ __launch_bounds__(256) void build_quads(const float* __restrict__ img,
                                                   float4* __restrict__ quad) {
    int idx = blockIdx.x * blockDim.x + threadIdx.x;   // 0 .. 512*512-1
    int r = idx >> 9, c = idx & 511;
    int r1 = min(r + 1, N_IMG - 1);
    int c1 = min(c + 1, N_IMG - 1);
    float4 q;
    q.x = img[(r  << 9) + c ];
    q.y = img[(r  << 9) + c1];
    q.z = img[(r1 << 9) + c ];
    q.w = img[(r1 << 9) + c1];
    quad[quad_index(r, c)] = q;
}

// Reference-exact masked bilinear sample (boundary bands only).
__device__ __forceinline__ float masked_sample(const float* __restrict__ img,
                                               float col, float row) {
    float rf = floorf(row), cf = floorf(col);
    float fr = row - rf,    fc = col - cf;
    int r0 = (int)rf, c0 = (int)cf;
    float wr0 = (r0 >=  0 && r0 < N_IMG)     ? (1.0f - fr) : 0.0f;
    float wr1 = (r0 >= -1 && r0 < N_IMG - 1) ? fr          : 0.0f;
    float wc0 = (c0 >=  0 && c0 < N_IMG)     ? (1.0f - fc) : 0.0f;
    float wc1 = (c0 >= -1 && c0 < N_IMG - 1) ? fc          : 0.0f;
    int rc0 = min(max(r0,     0), N_IMG - 1);
    int rc1 = min(max(r0 + 1, 0), N_IMG - 1);
    int cc0 = min(max(c0,     0), N_IMG - 1);
    int cc1 = min(max(c0 + 1, 0), N_IMG - 1);
    float v00 = img[(rc0 << 9) + cc0];
    float v01 = img[(rc0 << 9) + cc1];
    float v10 = img[(rc1 << 9) + cc0];
    float v11 = img[(rc1 << 9) + cc1];
    return wr0 * (wc0 * v00 + wc1 * v01) + wr1 * (wc0 * v10 + wc1 * v11);
}

// Clip [tlo,thi] to { t : lo <= v0 + t*dv <= hi }.
__device__ __forceinline__ void slab(float v0, float dv, float lo, float hi,
                                     float& tlo, float& thi) {
    if (fabsf(dv) < 1e-8f) {
        if (v0 < lo || v0 > hi) { tlo = 1.0f; thi = 0.0f; }   // empty
    } else {
        float inv = 1.0f / dv;
        float ta = (lo - v0) * inv;
        float tb = (hi - v0) * inv;
        tlo = fmaxf(tlo, fminf(ta, tb));
        thi = fminf(thi, fmaxf(ta, tb));
    }
}

__global__ __launch_bounds__(256) void fanbeam_kernel(const float* __restrict__ img,
                                                      const float4* __restrict__ quad,
                                                      float* __restrict__ out) {
    const int gid  = blockIdx.x * blockDim.x + threadIdx.x;
    const int ray  = gid >> 6;          // one wave64 per ray
    const int lane = threadIdx.x & 63;
    if (ray >= N_ANGLES * N_DET) return;

    const int a = ray / N_DET;
    const int d = ray - a * N_DET;

    // f32 trig (error ~1e-7 rad -> ~6e-5 px; validated passing in R8).
    float beta = (2.0f * (float)a / 25.0f) * 3.14159265358979323846f;
    float c, s;
    __sincosf(beta, &s, &c);
    float t = ((float)d - (N_DET - 1) * 0.5f) * DET_SPACING;
    float srcx = -SRC_DIST * s;
    float srcy =  SRC_DIST * c;
    float dx = (t * c + DET_DIST * s) - srcx;
    float dy = (t * s - DET_DIST * c) - srcy;
    float seg = sqrtf(dx * dx + dy * dy);

    const float half = (N_IMG - 1) * 0.5f;   // 255.5
    const float col0 = srcx + half;
    const float row0 = half - srcy;
    const float drow = -dy;
    const float inv_n = 1.0f / N_SAMPLES;

    // Outer window: outside col/row in (-1, 512) every corner weight is 0.
    float tA = 0.0f, tB = 1.0f;
    slab(col0, dx,   -1.01f, 512.01f, tA, tB);
    slab(row0, drow, -1.01f, 512.01f, tA, tB);
    int i_lo, i_hi;
    if (tB < tA) { i_lo = 1; i_hi = 0; }
    else {
        i_lo = max(0,             (int)floorf(tA * N_SAMPLES - 0.5f) - 1);
        i_hi = min(N_SAMPLES - 1, (int)ceilf (tB * N_SAMPLES - 0.5f) + 1);
    }

    // Interior window: col,row in [0.01, 510.99] -> r0,c0 in [0,510], all
    // four corners valid; quads cover r+1/c+1 up to 511 with real values.
    float tC = 0.0f, tD = 1.0f;
    slab(col0, dx,   0.01f, 510.99f, tC, tD);
    slab(row0, drow, 0.01f, 510.99f, tC, tD);
    int j_lo, j_hi;
    if (tD < tC) { j_lo = 1; j_hi = 0; }
    else {
        j_lo = (int)ceilf (tC * N_SAMPLES - 0.5f) + 1;
        j_hi = (int)floorf(tD * N_SAMPLES - 0.5f) - 1;
    }
    j_lo = max(j_lo, i_lo);
    j_hi = min(j_hi, i_hi);

    float acc = 0.0f;

    if (j_lo > j_hi) {
        for (int i = i_lo + lane; i <= i_hi; i += 64) {
            float ts  = ((float)i + 0.5f) * inv_n;
            acc += masked_sample(img, fmaf(ts, dx, col0), fmaf(ts, drow, row0));
        }
    } else {
        // Leading boundary band (reference-exact masked path).
        for (int i = i_lo + lane; i < j_lo; i += 64) {
            float ts  = ((float)i + 0.5f) * inv_n;
            acc += masked_sample(img, fmaf(ts, dx, col0), fmaf(ts, drow, row0));
        }
        // Interior fast path: ONE 16 B gather per sample from the 2x2-blocked
        // quad array (64 B line == 2x2-pixel patch -> line reuse for rays of
        // any orientation).
        #pragma unroll 2
        for (int i = j_lo + lane; i <= j_hi; i += 64) {
            float ts  = ((float)i + 0.5f) * inv_n;
            float col = fmaf(ts, dx,   col0);
            float row = fmaf(ts, drow, row0);
            float cf = floorf(col), rf = floorf(row);
            float fc = col - cf,    fr = row - rf;
            int ci = min(max((int)cf, 0), N_IMG - 2);
            int ri = min(max((int)rf, 0), N_IMG - 2);
            float4 q = quad[quad_index(ri, ci)];
            float top = fmaf(fc, q.y - q.x, q.x);
            float bot = fmaf(fc, q.w - q.z, q.z);
            acc += fmaf(fr, bot - top, top);
        }
        // Trailing boundary band.
        for (int i = max(j_hi + 1, i_lo) + lane; i <= i_hi; i += 64) {
            float ts  = ((float)i + 0.5f) * inv_n;
            acc += masked_sample(img, fmaf(ts, dx, col0), fmaf(ts, drow, row0));
        }
    }

    #pragma unroll
    for (int off = 32; off > 0; off >>= 1)
        acc += __shfl_down(acc, off, 64);

    if (lane == 0) out[ray] = acc * (seg * inv_n);
}

extern "C" void kernel_launch(void* const* d_in, const int* in_sizes, int n_in,
                              void* d_out, int out_size, void* d_ws, size_t ws_size,
                              hipStream_t stream) {
    const float* img = (const float*)d_in[0];
    float* out = (float*)d_out;
    float4* quad = (float4*)d_ws;                      // 512*512*16 B = 4 MB

    build_quads<<<(N_IMG * N_IMG) / 256, 256, 0, stream>>>(img, quad);

    const int n_rays = N_ANGLES * N_DET;               // 12800
    const int threads = 256;                           // 4 waves = 4 rays/block
    const int blocks = (n_rays * 64 + threads - 1) / threads;   // 3200
    fanbeam_kernel<<<blocks, threads, 0, stream>>>(img, quad, out);
}